// Round 17
// baseline (164.626 us; speedup 1.0000x reference)
//
#include <hip/hip_runtime.h>
#include <hip/hip_bf16.h>

typedef unsigned int u32;
typedef unsigned char u8;
typedef unsigned short u16;
using f32x4  = __attribute__((ext_vector_type(4))) float;
using f32x16 = __attribute__((ext_vector_type(16))) float;
using u32x4  = __attribute__((ext_vector_type(4))) u32;
using s16x8  = __attribute__((ext_vector_type(8))) short;

#define DEV static __device__ __forceinline__

DEV u32 pk2(float a, float b) {
  u16 lo = __builtin_bit_cast(u16, __float2bfloat16(a));
  u16 hi = __builtin_bit_cast(u16, __float2bfloat16(b));
  return (u32)lo | ((u32)hi << 16);
}

DEV f32x16 MFMA32(u32x4 a, u32x4 b, f32x16 c) {
  return __builtin_amdgcn_mfma_f32_32x32x16_bf16(
      __builtin_bit_cast(s16x8, a), __builtin_bit_cast(s16x8, b), c, 0, 0, 0);
}

DEV void pl32swap(u32& a, u32& b) {
  asm volatile("v_permlane32_swap_b32 %0, %1" : "+v"(a), "+v"(b));
}

typedef const __attribute__((address_space(1))) u32 gu32;
typedef __attribute__((address_space(3))) u32 lu32;

DEV void load_lds16(const void* g, void* l) {
  __builtin_amdgcn_global_load_lds((gu32*)g, (lu32*)l, 16, 0, 0);
}

DEV u16 tq1(float v, float thr) {
  return (fabsf(v) > thr) ? (v > 0.f ? (u16)0x3F80 : (u16)0xBF80) : (u16)0;
}
DEV u32 tq2(float a, float b, float thr) {
  return (u32)tq1(a, thr) | ((u32)tq1(b, thr) << 16);
}

// ======== k_gate: 512 blocks, one thread per token (L1-tiled column chunks) ====
__global__ void k_gate(const float* __restrict__ x, const float* __restrict__ wg,
                       const float* __restrict__ bg, float* __restrict__ gw,
                       u8* __restrict__ maskA, u32* __restrict__ hist) {
  const int tid = threadIdx.x;
  __shared__ float s_wg[1024];  // [8 e][128 d]
  __shared__ float s_bg[8];
  __shared__ u32 lh[256];
  ((float4*)s_wg)[tid] = ((const float4*)wg)[tid];
  if (tid < 8) s_bg[tid] = bg[tid];
  lh[tid] = 0;
  __syncthreads();

  int t = blockIdx.x * 256 + tid;
  const float4* xr = (const float4*)(x + (size_t)t * 128);
  float lg[8];
  #pragma unroll
  for (int e = 0; e < 8; ++e) lg[e] = s_bg[e];
  // column-chunked: per-wave live x-window = 64 rows x 32 floats = 8KB (L1-safe)
  #pragma unroll
  for (int c = 0; c < 4; ++c) {
    #pragma unroll
    for (int ii = 0; ii < 8; ++ii) {
      int i = c * 8 + ii;
      float4 xv = xr[i];
      #pragma unroll
      for (int e = 0; e < 8; ++e) {
        f32x4 wv = *(const f32x4*)(s_wg + e * 128 + i * 4);
        lg[e] += xv.x * wv.x + xv.y * wv.y + xv.z * wv.z + xv.w * wv.w;
      }
    }
  }
  const float invT = 0.36787944117144233f;  // 1/e
  #pragma unroll
  for (int e = 0; e < 8; ++e) lg[e] *= invT;
  float mx = lg[0];
  #pragma unroll
  for (int e = 1; e < 8; ++e) mx = fmaxf(mx, lg[e]);
  float p[8], den = 0.f;
  #pragma unroll
  for (int e = 0; e < 8; ++e) { p[e] = __expf(lg[e] - mx); den += p[e]; }
  float inv = 1.f / den;
  #pragma unroll
  for (int e = 0; e < 8; ++e) p[e] *= inv;
  float gsel[8], wsum = 0.f;
  u32 m = 0;
  #pragma unroll
  for (int e = 0; e < 8; ++e) {
    int rank = 0;
    #pragma unroll
    for (int e2 = 0; e2 < 8; ++e2)
      rank += (p[e2] > p[e]) || (p[e2] == p[e] && e2 < e);
    bool sel = rank < 5;
    if (sel) m |= 1u << e;
    gsel[e] = sel ? p[e] : 0.f;
    wsum += gsel[e];
  }
  float r = 1.f / (wsum + 1e-8f);
  float* gwp = gw + (size_t)t * 8;
  *(f32x4*)gwp       = (f32x4){gsel[0] * r, gsel[1] * r, gsel[2] * r, gsel[3] * r};
  *(f32x4*)(gwp + 4) = (f32x4){gsel[4] * r, gsel[5] * r, gsel[6] * r, gsel[7] * r};
  maskA[t] = (u8)m;
  __syncthreads();
  atomicAdd(&lh[m], 1u);
  __syncthreads();
  if (lh[tid]) atomicAdd(&hist[tid << 5], lh[tid]);  // 128B-strided bins
}

// ==== k_img_scatter: image+alpha (0-255) | scatter (256-767) | order (768) ====
__global__ void k_img_scatter(const float* __restrict__ w1,
                              const float* __restrict__ w2,
                              char* __restrict__ img,
                              const u32* __restrict__ hist,
                              const u8* __restrict__ maskA,
                              u32* __restrict__ cur2, u32* __restrict__ perm,
                              u32* __restrict__ order, u32* __restrict__ umask) {
  const int tid = threadIdx.x;
  if (blockIdx.x < 256) {
    const int b = blockIdx.x;
    // each image block covers exactly one expert matrix -> compute its alpha
    const float* wsrc = (b < 128) ? (w1 + (size_t)(b >> 4) * 32768)
                                  : (w2 + (size_t)((b - 128) >> 4) * 32768);
    float s = 0.f;
    const float4* wv4 = (const float4*)wsrc;
    #pragma unroll
    for (int j = 0; j < 32; ++j) {
      float4 v = wv4[tid + j * 256];
      s += fabsf(v.x) + fabsf(v.y) + fabsf(v.z) + fabsf(v.w);
    }
    #pragma unroll
    for (int off = 32; off >= 1; off >>= 1) s += __shfl_down(s, off, 64);
    __shared__ float ws4[4];
    if ((tid & 63) == 0) ws4[tid >> 6] = s;
    __syncthreads();
    const float thr =
        0.5f * (ws4[0] + ws4[1] + ws4[2] + ws4[3]) * (1.f / 32768.f);

    int gid = b * 256 + tid;  // 65536 weight items (v8-proven layout)
    int l = gid & 63;
    int col = l & 31, hi = l >> 5;
    const float* src;
    char* dst;
    if (gid < 32768) {
      int ks = (gid >> 6) & 7;
      int n  = gid >> 9;
      int e  = n >> 3, ht = n & 7;
      int h  = ht * 32 + col;
      int k0 = ks * 16 + hi * 8;
      src = w1 + (size_t)e * 32768 + h * 128 + k0;
      dst = img + (size_t)n * 16384 + ks * 1024 + l * 16;
    } else {
      int id = gid - 32768;
      int sl = (id >> 6) & 7;
      int n  = id >> 9;
      int e  = n >> 3, c = n & 7;
      int ks2 = sl >> 2, ot = sl & 3;
      int o  = ot * 32 + col;
      int k0 = c * 32 + ks2 * 16 + hi * 8;
      src = w2 + (size_t)e * 32768 + o * 256 + k0;
      dst = img + (size_t)n * 16384 + 8192 + sl * 1024 + l * 16;
    }
    float4 v0 = *(const float4*)src;
    float4 v1 = *(const float4*)(src + 4);
    *(uint4*)dst = make_uint4(tq2(v0.x, v0.y, thr), tq2(v0.z, v0.w, thr),
                              tq2(v1.x, v1.y, thr), tq2(v1.z, v1.w, thr));
    return;
  }
  if (blockIdx.x < 768) {
    // ---- scatter (counting sort, no padding)
    __shared__ u32 s[256], lh[256], lb[256];
    const int t = tid;
    u32 h = hist[t << 5];
    s[t] = h;
    lh[t] = 0;
    __syncthreads();
    #pragma unroll
    for (int o = 1; o < 256; o <<= 1) {
      u32 v = (t >= o) ? s[t - o] : 0u;
      __syncthreads();
      s[t] += v;
      __syncthreads();
    }
    const u32 pbase = s[t] - h;  // exclusive prefix
    int tkn = (blockIdx.x - 256) * 256 + t;
    u32 m = maskA[tkn];
    u32 r = atomicAdd(&lh[m], 1u);
    __syncthreads();
    if (lh[t]) lb[t] = pbase + atomicAdd(&cur2[t << 5], lh[t]);
    __syncthreads();
    perm[lb[m] + r] = (u32)tkn;
    return;
  }
  // ---- order block: per-main-block expert union + LPT dispatch order
  __shared__ u32 sh[256], sA[256], spfx[256];
  __shared__ u32 bcnt[4], bcur[4], boff[4];
  __shared__ u32 L[512];
  const int t = tid;
  u32 h = hist[t << 5];
  sh[t] = h;
  sA[t] = h;
  if (t < 4) { bcnt[t] = 0; bcur[t] = 0; }
  __syncthreads();
  #pragma unroll
  for (int o = 1; o < 256; o <<= 1) {
    u32 v = (t >= o) ? sA[t - o] : 0u;
    __syncthreads();
    sA[t] += v;
    __syncthreads();
  }
  spfx[t] = sA[t] - h;  // exclusive prefix
  __syncthreads();
  int c[2];
  int mb[2] = {t, t + 256};
  #pragma unroll
  for (int k = 0; k < 2; ++k) {
    u32 start = (u32)mb[k] * 256u, end = start + 256u;
    u32 un = 0;
    for (int m = 0; m < 256; ++m) {
      u32 p0 = spfx[m];
      if (sh[m] && p0 < end && p0 + sh[m] > start) un |= (u32)m;
    }
    umask[mb[k]] = un;
    c[k] = (int)__popc(un);         // 5..8
    atomicAdd(&bcnt[8 - c[k]], 1);  // bucket 0 = heaviest (cnt 8)
  }
  __syncthreads();
  if (t == 0) {
    boff[0] = 0;
    boff[1] = bcnt[0];
    boff[2] = bcnt[0] + bcnt[1];
    boff[3] = bcnt[0] + bcnt[1] + bcnt[2];
  }
  __syncthreads();
  #pragma unroll
  for (int k = 0; k < 2; ++k) {
    int q = 8 - c[k];
    u32 pos = boff[q] + atomicAdd(&bcur[q], 1);
    L[pos] = (u32)mb[k];
  }
  __syncthreads();
  // SNAKE FOLD: same-CU pair under XCD round-robin is (b, b+256); emit
  // round 1 heavy->light, round 2 light->heavy so pair = ranks (t, 511-t).
  order[t]       = L[t];
  order[256 + t] = L[511 - t];
}

// ================= main fused kernel (v14 body, unchanged) =================
#define B1_OFF 65536
#define G_OFF  73728
#define SMEM_BYTES 81920

__global__ __launch_bounds__(256, 2) void moe_main(
    const float* __restrict__ x, const float* __restrict__ b1g,
    const float* __restrict__ b2g, const char* __restrict__ img,
    const u32* __restrict__ perm, const float* __restrict__ gw,
    const u32* __restrict__ order, const u32* __restrict__ umask,
    float* __restrict__ out) {
  extern __shared__ char smem[];
  float* s_b1 = (float*)(smem + B1_OFF);  // [8 e][256 h] f32
  float* s_g  = (float*)(smem + G_OFF);   // [8 e][256 t] f32
  const int tid = threadIdx.x;
  const int w = tid >> 6, l = tid & 63;
  const int col = l & 31, hi = l >> 5;
  const int bid = (int)order[blockIdx.x];
  const int base = bid * 256;
  const u32 loff = (u32)(l * 16);

  const u32 bmask = __builtin_amdgcn_readfirstlane(umask[bid]);
  u32 elist = 0;
  int cnt = 0;
  #pragma unroll
  for (int e = 0; e < 8; ++e)
    if ((bmask >> e) & 1) { elist |= (u32)e << (4 * cnt); ++cnt; }
  elist = __builtin_amdgcn_readfirstlane(elist);
  const int iters = __builtin_amdgcn_readfirstlane(cnt * 4);

  // stage chunk-pair P (32KB) into slot; 8KB per wave
  auto stage_pair = [&](int P, int slot) {
    const char* src = img + (size_t)P * 32768 + w * 8192 + loff;
    char* dst = smem + slot * 32768 + w * 8192;
    #pragma unroll
    for (int i = 0; i < 8; ++i)
      load_lds16(src + i * 1024, dst + i * 1024);
  };

  stage_pair((elist & 7) * 4, 0);  // latency hides under fills below

  // ---- prologue: gather gate weights + b1 copy + xf (perm indices die here)
  u32x4 xf[2][8];
  {
    const u32 ptg = perm[base + tid];
    f32x4 gA = *(const f32x4*)(gw + (size_t)ptg * 8);
    f32x4 gB = *(const f32x4*)(gw + (size_t)ptg * 8 + 4);
    s_g[0 * 256 + tid] = gA.x; s_g[1 * 256 + tid] = gA.y;
    s_g[2 * 256 + tid] = gA.z; s_g[3 * 256 + tid] = gA.w;
    s_g[4 * 256 + tid] = gB.x; s_g[5 * 256 + tid] = gB.y;
    s_g[6 * 256 + tid] = gB.z; s_g[7 * 256 + tid] = gB.w;
    const float4* s = (const float4*)b1g;
    float4* d = (float4*)s_b1;
    d[tid] = s[tid];
    d[tid + 256] = s[tid + 256];

    #pragma unroll
    for (int tt = 0; tt < 2; ++tt) {
      const u32 pt = perm[base + w * 64 + tt * 32 + col];
      #pragma unroll
      for (int ks = 0; ks < 8; ++ks) {
        const float* xp = x + (size_t)pt * 128 + ks * 16 + hi * 8;
        float4 v0 = *(const float4*)xp;
        float4 v1 = *(const float4*)(xp + 4);
        xf[tt][ks] = (u32x4){pk2(v0.x, v0.y), pk2(v0.z, v0.w),
                             pk2(v1.x, v1.y), pk2(v1.z, v1.w)};
      }
    }
  }
  __syncthreads();  // s_g + b1 visible; drains stage0

  // ---- init acc2[ot][tt] = sum_e g[t][e]*b2[e][o] via one K=16 MFMA pass
  f32x16 acc2[4][2];
  {
    u32x4 gf[2];
    #pragma unroll
    for (int tt = 0; tt < 2; ++tt) {
      u32x4 v = (u32x4){0u, 0u, 0u, 0u};
      if (hi == 0) {
        int t = w * 64 + tt * 32 + col;
        v = (u32x4){pk2(s_g[0 * 256 + t], s_g[1 * 256 + t]),
                    pk2(s_g[2 * 256 + t], s_g[3 * 256 + t]),
                    pk2(s_g[4 * 256 + t], s_g[5 * 256 + t]),
                    pk2(s_g[6 * 256 + t], s_g[7 * 256 + t])};
      }
      gf[tt] = v;
    }
    #pragma unroll
    for (int ot = 0; ot < 4; ++ot) {
      u32x4 af = (u32x4){0u, 0u, 0u, 0u};
      if (hi == 0) {
        int o = ot * 32 + col;
        af = (u32x4){pk2(b2g[0 * 128 + o], b2g[1 * 128 + o]),
                     pk2(b2g[2 * 128 + o], b2g[3 * 128 + o]),
                     pk2(b2g[4 * 128 + o], b2g[5 * 128 + o]),
                     pk2(b2g[6 * 128 + o], b2g[7 * 128 + o])};
      }
      f32x16 z{};
      #pragma unroll
      for (int tt = 0; tt < 2; ++tt) acc2[ot][tt] = MFMA32(af, gf[tt], z);
    }
  }

  // ---- one chunk (tt=2): G1 16 MFMA -> EPI -> G2 16 MFMA (v8-proven)
  auto chunk = [&](const char* cb, int e, int ht, float g0, float g1) {
    f32x16 a1_0{}, a1_1{};
    __builtin_amdgcn_s_setprio(1);
    #pragma unroll
    for (int ks = 0; ks < 8; ++ks) {
      u32x4 f = *(const u32x4*)(cb + ks * 1024 + loff);
      a1_0 = MFMA32(f, xf[0][ks], a1_0);
      a1_1 = MFMA32(f, xf[1][ks], a1_1);
    }
    __builtin_amdgcn_s_setprio(0);

    const float* b1b = s_b1 + e * 256 + ht * 32 + hi * 4;
    u32x4 hf[2][2];
    #pragma unroll
    for (int tt = 0; tt < 2; ++tt) {
      const f32x16& a1 = tt ? a1_1 : a1_0;
      const float g = tt ? g1 : g0;
      u32 u[8];
      #pragma unroll
      for (int rg = 0; rg < 4; ++rg) {
        f32x4 bb = *(const f32x4*)(b1b + rg * 8);
        float h0 = fmaxf(a1[rg * 4 + 0] + bb.x, 0.f) * g;
        float h1 = fmaxf(a1[rg * 4 + 1] + bb.y, 0.f) * g;
        float h2 = fmaxf(a1[rg * 4 + 2] + bb.z, 0.f) * g;
        float h3 = fmaxf(a1[rg * 4 + 3] + bb.w, 0.f) * g;
        u[rg * 2 + 0] = pk2(h0, h1);
        u[rg * 2 + 1] = pk2(h2, h3);
      }
      pl32swap(u[0], u[2]);
      pl32swap(u[1], u[3]);
      pl32swap(u[4], u[6]);
      pl32swap(u[5], u[7]);
      hf[0][tt] = (u32x4){u[0], u[1], u[2], u[3]};
      hf[1][tt] = (u32x4){u[4], u[5], u[6], u[7]};
    }

    __builtin_amdgcn_s_setprio(1);
    #pragma unroll
    for (int ks2 = 0; ks2 < 2; ++ks2) {
      #pragma unroll
      for (int ot = 0; ot < 4; ++ot) {
        u32x4 af = *(const u32x4*)(cb + 8192 + (ks2 * 4 + ot) * 1024 + loff);
        acc2[ot][0] = MFMA32(af, hf[ks2][0], acc2[ot][0]);
        acc2[ot][1] = MFMA32(af, hf[ks2][1], acc2[ot][1]);
      }
    }
    __builtin_amdgcn_s_setprio(0);
  };

  // ---- main loop: iters chunk-pair iters; 1 barrier per 64 MFMA/wave
  #pragma unroll 1
  for (int i = 0; i < iters; ++i) {
    asm volatile("s_waitcnt vmcnt(0)" ::: "memory");  // stage from i-1 landed
    __builtin_amdgcn_s_barrier();
    __builtin_amdgcn_sched_barrier(0);
    if (i + 1 < iters) {
      const int j = i + 1;
      const int ej = (elist >> (4 * (j >> 2))) & 7;
      stage_pair(ej * 4 + (j & 3), j & 1);
    }
    const int ei = (elist >> (4 * (i >> 2))) & 7;
    const int ht0 = (i & 3) * 2;
    const float g0 = s_g[ei * 256 + w * 64 + col];
    const float g1 = s_g[ei * 256 + w * 64 + 32 + col];
    const char* buf = smem + (i & 1) * 32768;
    chunk(buf, ei, ht0, g0, g1);
    __builtin_amdgcn_sched_barrier(0);  // no cross-chunk frag hoisting
    chunk(buf + 16384, ei, ht0 + 1, g0, g1);
  }

  // ---- epilogue: reload perm (L2-hot) and scatter rows
  #pragma unroll
  for (int tt = 0; tt < 2; ++tt) {
    const u32 pt = perm[base + w * 64 + tt * 32 + col];
    #pragma unroll
    for (int ot = 0; ot < 4; ++ot) {
      const f32x16& a = acc2[ot][tt];
      float* op = out + (size_t)pt * 128 + ot * 32 + hi * 4;
      #pragma unroll
      for (int rg = 0; rg < 4; ++rg)
        *(f32x4*)(op + rg * 8) =
            (f32x4){a[rg * 4 + 0], a[rg * 4 + 1], a[rg * 4 + 2], a[rg * 4 + 3]};
    }
  }
}

extern "C" void kernel_launch(void* const* d_in, const int* in_sizes, int n_in,
                              void* d_out, int out_size, void* d_ws, size_t ws_size,
                              hipStream_t stream) {
  const float* x  = (const float*)d_in[0];
  const float* w1 = (const float*)d_in[1];
  const float* b1 = (const float*)d_in[2];
  const float* w2 = (const float*)d_in[3];
  const float* b2 = (const float*)d_in[4];
  const float* wg = (const float*)d_in[5];
  const float* bg = (const float*)d_in[6];
  float* out = (float*)d_out;

  int ntok = in_sizes[0] / 128;    // 131072
  int nblk = ntok / 256;           // 512

  // ws layout (bytes)
  char* ws = (char*)d_ws;
  char*  img    = ws;                        // 1,048,576
  u32*   hist   = (u32*)(ws + 1048576);      // 32,768 (128B-strided bins)
  u32*   cur2   = (u32*)(ws + 1081344);      // 32,768
  u32*   order  = (u32*)(ws + 1114112);      // 2,048
  u32*   umask  = (u32*)(ws + 1116160);      // 2,048
  u8*    maskA  = (u8*)(ws + 1118208);       // 131,072
  u32*   perm   = (u32*)(ws + 1249280);      // 524,288
  float* gw     = (float*)(ws + 1773568);    // 4,194,304
  if (ws_size < 5967872) return;

  hipMemsetAsync(hist, 0, 65536, stream);    // hist + cur2
  k_gate<<<nblk, 256, 0, stream>>>(x, wg, bg, gw, maskA, hist);
  k_img_scatter<<<768 + 1, 256, 0, stream>>>(w1, w2, img, hist, maskA,
                                             cur2, perm, order, umask);

  hipFuncSetAttribute(reinterpret_cast<const void*>(moe_main),
                      hipFuncAttributeMaxDynamicSharedMemorySize, SMEM_BYTES);
  moe_main<<<nblk, 256, SMEM_BYTES, stream>>>(x, b1, b2, img, perm, gw,
                                              order, umask, out);
}

// Round 19
// 162.253 us; speedup vs baseline: 1.0146x; 1.0146x over previous
//
#include <hip/hip_runtime.h>
#include <hip/hip_bf16.h>

typedef unsigned int u32;
typedef unsigned char u8;
typedef unsigned short u16;
using f32x4  = __attribute__((ext_vector_type(4))) float;
using f32x16 = __attribute__((ext_vector_type(16))) float;
using u32x4  = __attribute__((ext_vector_type(4))) u32;
using s16x8  = __attribute__((ext_vector_type(8))) short;

#define DEV static __device__ __forceinline__

DEV u32 pk2(float a, float b) {
  u16 lo = __builtin_bit_cast(u16, __float2bfloat16(a));
  u16 hi = __builtin_bit_cast(u16, __float2bfloat16(b));
  return (u32)lo | ((u32)hi << 16);
}

DEV f32x16 MFMA32(u32x4 a, u32x4 b, f32x16 c) {
  return __builtin_amdgcn_mfma_f32_32x32x16_bf16(
      __builtin_bit_cast(s16x8, a), __builtin_bit_cast(s16x8, b), c, 0, 0, 0);
}

DEV void pl32swap(u32& a, u32& b) {
  asm volatile("v_permlane32_swap_b32 %0, %1" : "+v"(a), "+v"(b));
}

typedef const __attribute__((address_space(1))) u32 gu32;
typedef __attribute__((address_space(3))) u32 lu32;

DEV void load_lds16(const void* g, void* l) {
  __builtin_amdgcn_global_load_lds((gu32*)g, (lu32*)l, 16, 0, 0);
}

DEV u16 tq1(float v, float thr) {
  return (fabsf(v) > thr) ? (v > 0.f ? (u16)0x3F80 : (u16)0xBF80) : (u16)0;
}
DEV u32 tq2(float a, float b, float thr) {
  return (u32)tq1(a, thr) | ((u32)tq1(b, thr) << 16);
}

// ==== k1: weight image+alpha (blocks 0-255) CONCURRENT with gate (256-767) ====
__global__ void k1_img_gate(const float* __restrict__ w1,
                            const float* __restrict__ w2,
                            char* __restrict__ img, const float* __restrict__ x,
                            const float* __restrict__ wg,
                            const float* __restrict__ bg, float* __restrict__ gw,
                            u8* __restrict__ maskA, u32* __restrict__ hist) {
  const int tid = threadIdx.x;
  if (blockIdx.x < 256) {
    const int b = blockIdx.x;
    // each image block covers exactly one expert matrix -> compute its alpha
    const float* wsrc = (b < 128) ? (w1 + (size_t)(b >> 4) * 32768)
                                  : (w2 + (size_t)((b - 128) >> 4) * 32768);
    float s = 0.f;
    const float4* wv4 = (const float4*)wsrc;
    #pragma unroll
    for (int j = 0; j < 32; ++j) {
      float4 v = wv4[tid + j * 256];
      s += fabsf(v.x) + fabsf(v.y) + fabsf(v.z) + fabsf(v.w);
    }
    #pragma unroll
    for (int off = 32; off >= 1; off >>= 1) s += __shfl_down(s, off, 64);
    __shared__ float ws4[4];
    if ((tid & 63) == 0) ws4[tid >> 6] = s;
    __syncthreads();
    const float thr =
        0.5f * (ws4[0] + ws4[1] + ws4[2] + ws4[3]) * (1.f / 32768.f);

    int gid = b * 256 + tid;  // 65536 weight items (v8-proven layout)
    int l = gid & 63;
    int col = l & 31, hi = l >> 5;
    const float* src;
    char* dst;
    if (gid < 32768) {
      int ks = (gid >> 6) & 7;
      int n  = gid >> 9;
      int e  = n >> 3, ht = n & 7;
      int h  = ht * 32 + col;
      int k0 = ks * 16 + hi * 8;
      src = w1 + (size_t)e * 32768 + h * 128 + k0;
      dst = img + (size_t)n * 16384 + ks * 1024 + l * 16;
    } else {
      int id = gid - 32768;
      int sl = (id >> 6) & 7;
      int n  = id >> 9;
      int e  = n >> 3, c = n & 7;
      int ks2 = sl >> 2, ot = sl & 3;
      int o  = ot * 32 + col;
      int k0 = c * 32 + ks2 * 16 + hi * 8;
      src = w2 + (size_t)e * 32768 + o * 256 + k0;
      dst = img + (size_t)n * 16384 + 8192 + sl * 1024 + l * 16;
    }
    float4 v0 = *(const float4*)src;
    float4 v1 = *(const float4*)(src + 4);
    *(uint4*)dst = make_uint4(tq2(v0.x, v0.y, thr), tq2(v0.z, v0.w, thr),
                              tq2(v1.x, v1.y, thr), tq2(v1.z, v1.w, thr));
    return;
  }
  // ---- gate: one thread per token, L1-tiled column chunks
  __shared__ float s_wg[1024];  // [8 e][128 d]
  __shared__ float s_bg[8];
  __shared__ u32 lh[256];
  ((float4*)s_wg)[tid] = ((const float4*)wg)[tid];
  if (tid < 8) s_bg[tid] = bg[tid];
  lh[tid] = 0;
  __syncthreads();

  int t = (blockIdx.x - 256) * 256 + tid;
  const float4* xr = (const float4*)(x + (size_t)t * 128);
  float lg[8];
  #pragma unroll
  for (int e = 0; e < 8; ++e) lg[e] = s_bg[e];
  #pragma unroll
  for (int c = 0; c < 4; ++c) {
    #pragma unroll
    for (int ii = 0; ii < 8; ++ii) {
      int i = c * 8 + ii;
      float4 xv = xr[i];
      #pragma unroll
      for (int e = 0; e < 8; ++e) {
        f32x4 wv = *(const f32x4*)(s_wg + e * 128 + i * 4);
        lg[e] += xv.x * wv.x + xv.y * wv.y + xv.z * wv.z + xv.w * wv.w;
      }
    }
  }
  const float invT = 0.36787944117144233f;  // 1/e
  #pragma unroll
  for (int e = 0; e < 8; ++e) lg[e] *= invT;
  float mx = lg[0];
  #pragma unroll
  for (int e = 1; e < 8; ++e) mx = fmaxf(mx, lg[e]);
  float p[8], den = 0.f;
  #pragma unroll
  for (int e = 0; e < 8; ++e) { p[e] = __expf(lg[e] - mx); den += p[e]; }
  float inv = 1.f / den;
  #pragma unroll
  for (int e = 0; e < 8; ++e) p[e] *= inv;
  float gsel[8], wsum = 0.f;
  u32 m = 0;
  #pragma unroll
  for (int e = 0; e < 8; ++e) {
    int rank = 0;
    #pragma unroll
    for (int e2 = 0; e2 < 8; ++e2)
      rank += (p[e2] > p[e]) || (p[e2] == p[e] && e2 < e);
    bool sel = rank < 5;
    if (sel) m |= 1u << e;
    gsel[e] = sel ? p[e] : 0.f;
    wsum += gsel[e];
  }
  float r = 1.f / (wsum + 1e-8f);
  float* gwp = gw + (size_t)t * 8;
  *(f32x4*)gwp       = (f32x4){gsel[0] * r, gsel[1] * r, gsel[2] * r, gsel[3] * r};
  *(f32x4*)(gwp + 4) = (f32x4){gsel[4] * r, gsel[5] * r, gsel[6] * r, gsel[7] * r};
  maskA[t] = (u8)m;
  __syncthreads();
  atomicAdd(&lh[m], 1u);
  __syncthreads();
  if (lh[tid]) atomicAdd(&hist[tid << 5], lh[tid]);  // 128B-strided bins
}

// ==== k2: scatter (blocks 0-511) | order (block 512) ====
__global__ void k2_scatter(const u32* __restrict__ hist,
                           const u8* __restrict__ maskA, u32* __restrict__ cur2,
                           u32* __restrict__ perm, u32* __restrict__ order,
                           u32* __restrict__ umask) {
  const int t = threadIdx.x;
  if (blockIdx.x < 512) {
    __shared__ u32 s[256], lh[256], lb[256];
    u32 h = hist[t << 5];
    s[t] = h;
    lh[t] = 0;
    __syncthreads();
    #pragma unroll
    for (int o = 1; o < 256; o <<= 1) {
      u32 v = (t >= o) ? s[t - o] : 0u;
      __syncthreads();
      s[t] += v;
      __syncthreads();
    }
    const u32 pbase = s[t] - h;  // exclusive prefix
    int tkn = blockIdx.x * 256 + t;
    u32 m = maskA[tkn];
    u32 r = atomicAdd(&lh[m], 1u);
    __syncthreads();
    if (lh[t]) lb[t] = pbase + atomicAdd(&cur2[t << 5], lh[t]);
    __syncthreads();
    perm[lb[m] + r] = (u32)tkn;
    return;
  }
  // ---- order block: per-main-block expert union + LPT dispatch order
  __shared__ u32 sh[256], sA[256], spfx[256];
  __shared__ u32 bcnt[4], bcur[4], boff[4];
  __shared__ u32 L[512];
  u32 h = hist[t << 5];
  sh[t] = h;
  sA[t] = h;
  if (t < 4) { bcnt[t] = 0; bcur[t] = 0; }
  __syncthreads();
  #pragma unroll
  for (int o = 1; o < 256; o <<= 1) {
    u32 v = (t >= o) ? sA[t - o] : 0u;
    __syncthreads();
    sA[t] += v;
    __syncthreads();
  }
  spfx[t] = sA[t] - h;  // exclusive prefix
  __syncthreads();
  int c[2];
  int mb[2] = {t, t + 256};
  #pragma unroll
  for (int k = 0; k < 2; ++k) {
    u32 start = (u32)mb[k] * 256u, end = start + 256u;
    u32 un = 0;
    for (int m = 0; m < 256; ++m) {
      u32 p0 = spfx[m];
      if (sh[m] && p0 < end && p0 + sh[m] > start) un |= (u32)m;
    }
    umask[mb[k]] = un;
    c[k] = (int)__popc(un);         // 5..8
    atomicAdd(&bcnt[8 - c[k]], 1);  // bucket 0 = heaviest (cnt 8)
  }
  __syncthreads();
  if (t == 0) {
    boff[0] = 0;
    boff[1] = bcnt[0];
    boff[2] = bcnt[0] + bcnt[1];
    boff[3] = bcnt[0] + bcnt[1] + bcnt[2];
  }
  __syncthreads();
  #pragma unroll
  for (int k = 0; k < 2; ++k) {
    int q = 8 - c[k];
    u32 pos = boff[q] + atomicAdd(&bcur[q], 1);
    L[pos] = (u32)mb[k];
  }
  __syncthreads();
  // v16-proven emission: heavy+light adjacent AND anti-phased
  order[2 * t]     = L[t];
  order[2 * t + 1] = L[511 - t];
}

// ================= main fused kernel (v16 body, unchanged) =================
#define B1_OFF 65536
#define G_OFF  73728
#define SMEM_BYTES 81920

__global__ __launch_bounds__(256, 2) void moe_main(
    const float* __restrict__ x, const float* __restrict__ b1g,
    const float* __restrict__ b2g, const char* __restrict__ img,
    const u32* __restrict__ perm, const float* __restrict__ gw,
    const u32* __restrict__ order, const u32* __restrict__ umask,
    float* __restrict__ out) {
  extern __shared__ char smem[];
  float* s_b1 = (float*)(smem + B1_OFF);  // [8 e][256 h] f32
  float* s_g  = (float*)(smem + G_OFF);   // [8 e][256 t] f32
  const int tid = threadIdx.x;
  const int w = tid >> 6, l = tid & 63;
  const int col = l & 31, hi = l >> 5;
  const int bid = (int)order[blockIdx.x];
  const int base = bid * 256;
  const u32 loff = (u32)(l * 16);

  const u32 bmask = __builtin_amdgcn_readfirstlane(umask[bid]);
  u32 elist = 0;
  int cnt = 0;
  #pragma unroll
  for (int e = 0; e < 8; ++e)
    if ((bmask >> e) & 1) { elist |= (u32)e << (4 * cnt); ++cnt; }
  elist = __builtin_amdgcn_readfirstlane(elist);
  const int iters = __builtin_amdgcn_readfirstlane(cnt * 4);

  // stage chunk-pair P (32KB) into slot; 8KB per wave
  auto stage_pair = [&](int P, int slot) {
    const char* src = img + (size_t)P * 32768 + w * 8192 + loff;
    char* dst = smem + slot * 32768 + w * 8192;
    #pragma unroll
    for (int i = 0; i < 8; ++i)
      load_lds16(src + i * 1024, dst + i * 1024);
  };

  stage_pair((elist & 7) * 4, 0);  // latency hides under fills below

  // ---- prologue: gather gate weights + b1 copy + xf (perm indices die here)
  u32x4 xf[2][8];
  {
    const u32 ptg = perm[base + tid];
    f32x4 gA = *(const f32x4*)(gw + (size_t)ptg * 8);
    f32x4 gB = *(const f32x4*)(gw + (size_t)ptg * 8 + 4);
    s_g[0 * 256 + tid] = gA.x; s_g[1 * 256 + tid] = gA.y;
    s_g[2 * 256 + tid] = gA.z; s_g[3 * 256 + tid] = gA.w;
    s_g[4 * 256 + tid] = gB.x; s_g[5 * 256 + tid] = gB.y;
    s_g[6 * 256 + tid] = gB.z; s_g[7 * 256 + tid] = gB.w;
    const float4* s = (const float4*)b1g;
    float4* d = (float4*)s_b1;
    d[tid] = s[tid];
    d[tid + 256] = s[tid + 256];

    #pragma unroll
    for (int tt = 0; tt < 2; ++tt) {
      const u32 pt = perm[base + w * 64 + tt * 32 + col];
      #pragma unroll
      for (int ks = 0; ks < 8; ++ks) {
        const float* xp = x + (size_t)pt * 128 + ks * 16 + hi * 8;
        float4 v0 = *(const float4*)xp;
        float4 v1 = *(const float4*)(xp + 4);
        xf[tt][ks] = (u32x4){pk2(v0.x, v0.y), pk2(v0.z, v0.w),
                             pk2(v1.x, v1.y), pk2(v1.z, v1.w)};
      }
    }
  }
  __syncthreads();  // s_g + b1 visible; drains stage0

  // ---- init acc2[ot][tt] = sum_e g[t][e]*b2[e][o] via one K=16 MFMA pass
  f32x16 acc2[4][2];
  {
    u32x4 gf[2];
    #pragma unroll
    for (int tt = 0; tt < 2; ++tt) {
      u32x4 v = (u32x4){0u, 0u, 0u, 0u};
      if (hi == 0) {
        int t = w * 64 + tt * 32 + col;
        v = (u32x4){pk2(s_g[0 * 256 + t], s_g[1 * 256 + t]),
                    pk2(s_g[2 * 256 + t], s_g[3 * 256 + t]),
                    pk2(s_g[4 * 256 + t], s_g[5 * 256 + t]),
                    pk2(s_g[6 * 256 + t], s_g[7 * 256 + t])};
      }
      gf[tt] = v;
    }
    #pragma unroll
    for (int ot = 0; ot < 4; ++ot) {
      u32x4 af = (u32x4){0u, 0u, 0u, 0u};
      if (hi == 0) {
        int o = ot * 32 + col;
        af = (u32x4){pk2(b2g[0 * 128 + o], b2g[1 * 128 + o]),
                     pk2(b2g[2 * 128 + o], b2g[3 * 128 + o]),
                     pk2(b2g[4 * 128 + o], b2g[5 * 128 + o]),
                     pk2(b2g[6 * 128 + o], b2g[7 * 128 + o])};
      }
      f32x16 z{};
      #pragma unroll
      for (int tt = 0; tt < 2; ++tt) acc2[ot][tt] = MFMA32(af, gf[tt], z);
    }
  }

  // ---- one chunk (tt=2): G1 16 MFMA -> EPI -> G2 16 MFMA (v8-proven)
  auto chunk = [&](const char* cb, int e, int ht, float g0, float g1) {
    f32x16 a1_0{}, a1_1{};
    __builtin_amdgcn_s_setprio(1);
    #pragma unroll
    for (int ks = 0; ks < 8; ++ks) {
      u32x4 f = *(const u32x4*)(cb + ks * 1024 + loff);
      a1_0 = MFMA32(f, xf[0][ks], a1_0);
      a1_1 = MFMA32(f, xf[1][ks], a1_1);
    }
    __builtin_amdgcn_s_setprio(0);

    const float* b1b = s_b1 + e * 256 + ht * 32 + hi * 4;
    u32x4 hf[2][2];
    #pragma unroll
    for (int tt = 0; tt < 2; ++tt) {
      const f32x16& a1 = tt ? a1_1 : a1_0;
      const float g = tt ? g1 : g0;
      u32 u[8];
      #pragma unroll
      for (int rg = 0; rg < 4; ++rg) {
        f32x4 bb = *(const f32x4*)(b1b + rg * 8);
        float h0 = fmaxf(a1[rg * 4 + 0] + bb.x, 0.f) * g;
        float h1 = fmaxf(a1[rg * 4 + 1] + bb.y, 0.f) * g;
        float h2 = fmaxf(a1[rg * 4 + 2] + bb.z, 0.f) * g;
        float h3 = fmaxf(a1[rg * 4 + 3] + bb.w, 0.f) * g;
        u[rg * 2 + 0] = pk2(h0, h1);
        u[rg * 2 + 1] = pk2(h2, h3);
      }
      pl32swap(u[0], u[2]);
      pl32swap(u[1], u[3]);
      pl32swap(u[4], u[6]);
      pl32swap(u[5], u[7]);
      hf[0][tt] = (u32x4){u[0], u[1], u[2], u[3]};
      hf[1][tt] = (u32x4){u[4], u[5], u[6], u[7]};
    }

    __builtin_amdgcn_s_setprio(1);
    #pragma unroll
    for (int ks2 = 0; ks2 < 2; ++ks2) {
      #pragma unroll
      for (int ot = 0; ot < 4; ++ot) {
        u32x4 af = *(const u32x4*)(cb + 8192 + (ks2 * 4 + ot) * 1024 + loff);
        acc2[ot][0] = MFMA32(af, hf[ks2][0], acc2[ot][0]);
        acc2[ot][1] = MFMA32(af, hf[ks2][1], acc2[ot][1]);
      }
    }
    __builtin_amdgcn_s_setprio(0);
  };

  // ---- main loop: iters chunk-pair iters; 1 barrier per 64 MFMA/wave
  #pragma unroll 1
  for (int i = 0; i < iters; ++i) {
    asm volatile("s_waitcnt vmcnt(0)" ::: "memory");  // stage from i-1 landed
    __builtin_amdgcn_s_barrier();
    __builtin_amdgcn_sched_barrier(0);
    if (i + 1 < iters) {
      const int j = i + 1;
      const int ej = (elist >> (4 * (j >> 2))) & 7;
      stage_pair(ej * 4 + (j & 3), j & 1);
    }
    const int ei = (elist >> (4 * (i >> 2))) & 7;
    const int ht0 = (i & 3) * 2;
    const float g0 = s_g[ei * 256 + w * 64 + col];
    const float g1 = s_g[ei * 256 + w * 64 + 32 + col];
    const char* buf = smem + (i & 1) * 32768;
    chunk(buf, ei, ht0, g0, g1);
    __builtin_amdgcn_sched_barrier(0);  // no cross-chunk frag hoisting
    chunk(buf + 16384, ei, ht0 + 1, g0, g1);
  }

  // ---- epilogue: reload perm (L2-hot) and scatter rows
  #pragma unroll
  for (int tt = 0; tt < 2; ++tt) {
    const u32 pt = perm[base + w * 64 + tt * 32 + col];
    #pragma unroll
    for (int ot = 0; ot < 4; ++ot) {
      const f32x16& a = acc2[ot][tt];
      float* op = out + (size_t)pt * 128 + ot * 32 + hi * 4;
      #pragma unroll
      for (int rg = 0; rg < 4; ++rg)
        *(f32x4*)(op + rg * 8) =
            (f32x4){a[rg * 4 + 0], a[rg * 4 + 1], a[rg * 4 + 2], a[rg * 4 + 3]};
    }
  }
}

extern "C" void kernel_launch(void* const* d_in, const int* in_sizes, int n_in,
                              void* d_out, int out_size, void* d_ws, size_t ws_size,
                              hipStream_t stream) {
  const float* x  = (const float*)d_in[0];
  const float* w1 = (const float*)d_in[1];
  const float* b1 = (const float*)d_in[2];
  const float* w2 = (const float*)d_in[3];
  const float* b2 = (const float*)d_in[4];
  const float* wg = (const float*)d_in[5];
  const float* bg = (const float*)d_in[6];
  float* out = (float*)d_out;

  int ntok = in_sizes[0] / 128;    // 131072
  int nblk = ntok / 256;           // 512

  // ws layout (bytes)
  char* ws = (char*)d_ws;
  char*  img    = ws;                        // 1,048,576
  u32*   hist   = (u32*)(ws + 1048576);      // 32,768 (128B-strided bins)
  u32*   cur2   = (u32*)(ws + 1081344);      // 32,768
  u32*   order  = (u32*)(ws + 1114112);      // 2,048
  u32*   umask  = (u32*)(ws + 1116160);      // 2,048
  u8*    maskA  = (u8*)(ws + 1118208);       // 131,072
  u32*   perm   = (u32*)(ws + 1249280);      // 524,288
  float* gw     = (float*)(ws + 1773568);    // 4,194,304
  if (ws_size < 5967872) return;

  hipMemsetAsync(hist, 0, 65536, stream);    // hist + cur2
  k1_img_gate<<<256 + nblk, 256, 0, stream>>>(w1, w2, img, x, wg, bg,
                                              gw, maskA, hist);
  k2_scatter<<<nblk + 1, 256, 0, stream>>>(hist, maskA, cur2, perm, order,
                                           umask);

  hipFuncSetAttribute(reinterpret_cast<const void*>(moe_main),
                      hipFuncAttributeMaxDynamicSharedMemorySize, SMEM_BYTES);
  moe_main<<<nblk, 256, SMEM_BYTES, stream>>>(x, b1, b2, img, perm, gw,
                                              order, umask, out);
}

// Round 20
// 161.782 us; speedup vs baseline: 1.0176x; 1.0029x over previous
//
#include <hip/hip_runtime.h>
#include <hip/hip_bf16.h>

typedef unsigned int u32;
typedef unsigned char u8;
typedef unsigned short u16;
using f32x4  = __attribute__((ext_vector_type(4))) float;
using f32x16 = __attribute__((ext_vector_type(16))) float;
using u32x4  = __attribute__((ext_vector_type(4))) u32;
using s16x8  = __attribute__((ext_vector_type(8))) short;

#define DEV static __device__ __forceinline__

DEV u32 pk2(float a, float b) {
  u16 lo = __builtin_bit_cast(u16, __float2bfloat16(a));
  u16 hi = __builtin_bit_cast(u16, __float2bfloat16(b));
  return (u32)lo | ((u32)hi << 16);
}

DEV f32x16 MFMA32(u32x4 a, u32x4 b, f32x16 c) {
  return __builtin_amdgcn_mfma_f32_32x32x16_bf16(
      __builtin_bit_cast(s16x8, a), __builtin_bit_cast(s16x8, b), c, 0, 0, 0);
}

DEV void pl32swap(u32& a, u32& b) {
  asm volatile("v_permlane32_swap_b32 %0, %1" : "+v"(a), "+v"(b));
}

typedef const __attribute__((address_space(1))) u32 gu32;
typedef __attribute__((address_space(3))) u32 lu32;

DEV void load_lds16(const void* g, void* l) {
  __builtin_amdgcn_global_load_lds((gu32*)g, (lu32*)l, 16, 0, 0);
}

DEV u16 tq1(float v, float thr) {
  return (fabsf(v) > thr) ? (v > 0.f ? (u16)0x3F80 : (u16)0xBF80) : (u16)0;
}
DEV u32 tq2(float a, float b, float thr) {
  return (u32)tq1(a, thr) | ((u32)tq1(b, thr) << 16);
}

// ==== k1: weight image+alpha (blocks 0-255) CONCURRENT with gate (256-767) ====
// Gate uses v11-verified coalesced staging: x rows -> transposed LDS tile,
// conflict-free lane=token reads (fixes the one-row-per-lane L1 thrash).
__global__ void k1_img_gate(const float* __restrict__ w1,
                            const float* __restrict__ w2,
                            char* __restrict__ img, const float* __restrict__ x,
                            const float* __restrict__ wg,
                            const float* __restrict__ bg, float* __restrict__ gw,
                            u8* __restrict__ maskA, u32* __restrict__ hist) {
  const int tid = threadIdx.x;
  if (blockIdx.x < 256) {
    const int b = blockIdx.x;
    // each image block covers exactly one expert matrix -> compute its alpha
    const float* wsrc = (b < 128) ? (w1 + (size_t)(b >> 4) * 32768)
                                  : (w2 + (size_t)((b - 128) >> 4) * 32768);
    float s = 0.f;
    const float4* wv4 = (const float4*)wsrc;
    #pragma unroll
    for (int j = 0; j < 32; ++j) {
      float4 v = wv4[tid + j * 256];
      s += fabsf(v.x) + fabsf(v.y) + fabsf(v.z) + fabsf(v.w);
    }
    #pragma unroll
    for (int off = 32; off >= 1; off >>= 1) s += __shfl_down(s, off, 64);
    __shared__ float ws4[4];
    if ((tid & 63) == 0) ws4[tid >> 6] = s;
    __syncthreads();
    const float thr =
        0.5f * (ws4[0] + ws4[1] + ws4[2] + ws4[3]) * (1.f / 32768.f);

    int gid = b * 256 + tid;  // 65536 weight items (v8-proven layout)
    int l = gid & 63;
    int col = l & 31, hi = l >> 5;
    const float* src;
    char* dst;
    if (gid < 32768) {
      int ks = (gid >> 6) & 7;
      int n  = gid >> 9;
      int e  = n >> 3, ht = n & 7;
      int h  = ht * 32 + col;
      int k0 = ks * 16 + hi * 8;
      src = w1 + (size_t)e * 32768 + h * 128 + k0;
      dst = img + (size_t)n * 16384 + ks * 1024 + l * 16;
    } else {
      int id = gid - 32768;
      int sl = (id >> 6) & 7;
      int n  = id >> 9;
      int e  = n >> 3, c = n & 7;
      int ks2 = sl >> 2, ot = sl & 3;
      int o  = ot * 32 + col;
      int k0 = c * 32 + ks2 * 16 + hi * 8;
      src = w2 + (size_t)e * 32768 + o * 256 + k0;
      dst = img + (size_t)n * 16384 + 8192 + sl * 1024 + l * 16;
    }
    float4 v0 = *(const float4*)src;
    float4 v1 = *(const float4*)(src + 4);
    *(uint4*)dst = make_uint4(tq2(v0.x, v0.y, thr), tq2(v0.z, v0.w, thr),
                              tq2(v1.x, v1.y, thr), tq2(v1.z, v1.w, thr));
    return;
  }
  // ---- gate block: 256 tokens, 4 tiles of 64 (v11-verified math & layout)
  __shared__ f32x4 s_xT[32 * 66];  // [c4][row], transposed (conflict-free reads)
  __shared__ float s_wg[1024];     // [8][128]
  __shared__ float s_bg[8];
  __shared__ float s_lg[64 * 9];   // [tok][e] logits (with bg)
  __shared__ u32 lh[256];

  ((float4*)s_wg)[tid] = ((const float4*)wg)[tid];
  if (tid < 8) s_bg[tid] = bg[tid];
  lh[tid] = 0;

  const int tok_base = (blockIdx.x - 256) * 256;
  const int wv = tid >> 6;   // expert pair: wv, wv+4
  const int ln = tid & 63;   // token within tile

  #pragma unroll 1
  for (int t4 = 0; t4 < 4; ++t4) {
    __syncthreads();
    // stage 64 rows coalesced, transposed
    const float4* src = (const float4*)(x + (size_t)(tok_base + t4 * 64) * 128);
    #pragma unroll
    for (int k = 0; k < 8; ++k) {
      int f = tid + k * 256;  // 0..2047
      int row = f >> 5, c4 = f & 31;
      float4 v = src[f];
      s_xT[c4 * 66 + row] = (f32x4){v.x, v.y, v.z, v.w};
    }
    __syncthreads();
    // compute: wave wv -> experts {wv, wv+4}, lane -> token
    {
      const float* wr0 = s_wg + wv * 128;
      const float* wr1 = s_wg + (wv + 4) * 128;
      float a0 = 0.f, a1 = 0.f;
      #pragma unroll
      for (int i = 0; i < 32; ++i) {
        f32x4 xv = s_xT[i * 66 + ln];
        f32x4 w0 = *(const f32x4*)(wr0 + i * 4);
        f32x4 w1v = *(const f32x4*)(wr1 + i * 4);
        a0 += xv.x * w0.x + xv.y * w0.y + xv.z * w0.z + xv.w * w0.w;
        a1 += xv.x * w1v.x + xv.y * w1v.y + xv.z * w1v.z + xv.w * w1v.w;
      }
      s_lg[ln * 9 + wv]     = a0 + s_bg[wv];
      s_lg[ln * 9 + wv + 4] = a1 + s_bg[wv + 4];
    }
    __syncthreads();
    // finish: one thread per token (tid<64)
    if (tid < 64) {
      int t = tok_base + t4 * 64 + tid;
      const float invT = 0.36787944117144233f;  // 1/e
      float lg[8];
      #pragma unroll
      for (int e = 0; e < 8; ++e) lg[e] = s_lg[tid * 9 + e] * invT;
      float mx = lg[0];
      #pragma unroll
      for (int e = 1; e < 8; ++e) mx = fmaxf(mx, lg[e]);
      float p[8], den = 0.f;
      #pragma unroll
      for (int e = 0; e < 8; ++e) { p[e] = __expf(lg[e] - mx); den += p[e]; }
      float inv = 1.f / den;
      #pragma unroll
      for (int e = 0; e < 8; ++e) p[e] *= inv;
      float gsel[8], wsum = 0.f;
      u32 m = 0;
      #pragma unroll
      for (int e = 0; e < 8; ++e) {
        int rank = 0;
        #pragma unroll
        for (int e2 = 0; e2 < 8; ++e2)
          rank += (p[e2] > p[e]) || (p[e2] == p[e] && e2 < e);
        bool sel = rank < 5;
        if (sel) m |= 1u << e;
        gsel[e] = sel ? p[e] : 0.f;
        wsum += gsel[e];
      }
      float r = 1.f / (wsum + 1e-8f);
      float* gwp = gw + (size_t)t * 8;
      *(f32x4*)gwp       = (f32x4){gsel[0] * r, gsel[1] * r, gsel[2] * r, gsel[3] * r};
      *(f32x4*)(gwp + 4) = (f32x4){gsel[4] * r, gsel[5] * r, gsel[6] * r, gsel[7] * r};
      maskA[t] = (u8)m;
      atomicAdd(&lh[m], 1u);
    }
  }
  __syncthreads();
  if (lh[tid]) atomicAdd(&hist[tid << 5], lh[tid]);  // 128B-strided bins
}

// ==== k2: scatter (blocks 0-511) | order (block 512) ====
__global__ void k2_scatter(const u32* __restrict__ hist,
                           const u8* __restrict__ maskA, u32* __restrict__ cur2,
                           u32* __restrict__ perm, u32* __restrict__ order,
                           u32* __restrict__ umask) {
  const int t = threadIdx.x;
  if (blockIdx.x < 512) {
    __shared__ u32 s[256], lh[256], lb[256];
    u32 h = hist[t << 5];
    s[t] = h;
    lh[t] = 0;
    __syncthreads();
    #pragma unroll
    for (int o = 1; o < 256; o <<= 1) {
      u32 v = (t >= o) ? s[t - o] : 0u;
      __syncthreads();
      s[t] += v;
      __syncthreads();
    }
    const u32 pbase = s[t] - h;  // exclusive prefix
    int tkn = blockIdx.x * 256 + t;
    u32 m = maskA[tkn];
    u32 r = atomicAdd(&lh[m], 1u);
    __syncthreads();
    if (lh[t]) lb[t] = pbase + atomicAdd(&cur2[t << 5], lh[t]);
    __syncthreads();
    perm[lb[m] + r] = (u32)tkn;
    return;
  }
  // ---- order block: per-main-block expert union + LPT dispatch order
  __shared__ u32 sh[256], sA[256], spfx[256];
  __shared__ u32 bcnt[4], bcur[4], boff[4];
  __shared__ u32 L[512];
  u32 h = hist[t << 5];
  sh[t] = h;
  sA[t] = h;
  if (t < 4) { bcnt[t] = 0; bcur[t] = 0; }
  __syncthreads();
  #pragma unroll
  for (int o = 1; o < 256; o <<= 1) {
    u32 v = (t >= o) ? sA[t - o] : 0u;
    __syncthreads();
    sA[t] += v;
    __syncthreads();
  }
  spfx[t] = sA[t] - h;  // exclusive prefix
  __syncthreads();
  int c[2];
  int mb[2] = {t, t + 256};
  #pragma unroll
  for (int k = 0; k < 2; ++k) {
    u32 start = (u32)mb[k] * 256u, end = start + 256u;
    u32 un = 0;
    for (int m = 0; m < 256; ++m) {
      u32 p0 = spfx[m];
      if (sh[m] && p0 < end && p0 + sh[m] > start) un |= (u32)m;
    }
    umask[mb[k]] = un;
    c[k] = (int)__popc(un);         // 5..8
    atomicAdd(&bcnt[8 - c[k]], 1);  // bucket 0 = heaviest (cnt 8)
  }
  __syncthreads();
  if (t == 0) {
    boff[0] = 0;
    boff[1] = bcnt[0];
    boff[2] = bcnt[0] + bcnt[1];
    boff[3] = bcnt[0] + bcnt[1] + bcnt[2];
  }
  __syncthreads();
  #pragma unroll
  for (int k = 0; k < 2; ++k) {
    int q = 8 - c[k];
    u32 pos = boff[q] + atomicAdd(&bcur[q], 1);
    L[pos] = (u32)mb[k];
  }
  __syncthreads();
  // v16-proven emission: heavy+light adjacent AND anti-phased
  order[2 * t]     = L[t];
  order[2 * t + 1] = L[511 - t];
}

// ================= main fused kernel (v16 body, unchanged) =================
#define B1_OFF 65536
#define G_OFF  73728
#define SMEM_BYTES 81920

__global__ __launch_bounds__(256, 2) void moe_main(
    const float* __restrict__ x, const float* __restrict__ b1g,
    const float* __restrict__ b2g, const char* __restrict__ img,
    const u32* __restrict__ perm, const float* __restrict__ gw,
    const u32* __restrict__ order, const u32* __restrict__ umask,
    float* __restrict__ out) {
  extern __shared__ char smem[];
  float* s_b1 = (float*)(smem + B1_OFF);  // [8 e][256 h] f32
  float* s_g  = (float*)(smem + G_OFF);   // [8 e][256 t] f32
  const int tid = threadIdx.x;
  const int w = tid >> 6, l = tid & 63;
  const int col = l & 31, hi = l >> 5;
  const int bid = (int)order[blockIdx.x];
  const int base = bid * 256;
  const u32 loff = (u32)(l * 16);

  const u32 bmask = __builtin_amdgcn_readfirstlane(umask[bid]);
  u32 elist = 0;
  int cnt = 0;
  #pragma unroll
  for (int e = 0; e < 8; ++e)
    if ((bmask >> e) & 1) { elist |= (u32)e << (4 * cnt); ++cnt; }
  elist = __builtin_amdgcn_readfirstlane(elist);
  const int iters = __builtin_amdgcn_readfirstlane(cnt * 4);

  // stage chunk-pair P (32KB) into slot; 8KB per wave
  auto stage_pair = [&](int P, int slot) {
    const char* src = img + (size_t)P * 32768 + w * 8192 + loff;
    char* dst = smem + slot * 32768 + w * 8192;
    #pragma unroll
    for (int i = 0; i < 8; ++i)
      load_lds16(src + i * 1024, dst + i * 1024);
  };

  stage_pair((elist & 7) * 4, 0);  // latency hides under fills below

  // ---- prologue: gather gate weights + b1 copy + xf (perm indices die here)
  u32x4 xf[2][8];
  {
    const u32 ptg = perm[base + tid];
    f32x4 gA = *(const f32x4*)(gw + (size_t)ptg * 8);
    f32x4 gB = *(const f32x4*)(gw + (size_t)ptg * 8 + 4);
    s_g[0 * 256 + tid] = gA.x; s_g[1 * 256 + tid] = gA.y;
    s_g[2 * 256 + tid] = gA.z; s_g[3 * 256 + tid] = gA.w;
    s_g[4 * 256 + tid] = gB.x; s_g[5 * 256 + tid] = gB.y;
    s_g[6 * 256 + tid] = gB.z; s_g[7 * 256 + tid] = gB.w;
    const float4* s = (const float4*)b1g;
    float4* d = (float4*)s_b1;
    d[tid] = s[tid];
    d[tid + 256] = s[tid + 256];

    #pragma unroll
    for (int tt = 0; tt < 2; ++tt) {
      const u32 pt = perm[base + w * 64 + tt * 32 + col];
      #pragma unroll
      for (int ks = 0; ks < 8; ++ks) {
        const float* xp = x + (size_t)pt * 128 + ks * 16 + hi * 8;
        float4 v0 = *(const float4*)xp;
        float4 v1 = *(const float4*)(xp + 4);
        xf[tt][ks] = (u32x4){pk2(v0.x, v0.y), pk2(v0.z, v0.w),
                             pk2(v1.x, v1.y), pk2(v1.z, v1.w)};
      }
    }
  }
  __syncthreads();  // s_g + b1 visible; drains stage0

  // ---- init acc2[ot][tt] = sum_e g[t][e]*b2[e][o] via one K=16 MFMA pass
  f32x16 acc2[4][2];
  {
    u32x4 gf[2];
    #pragma unroll
    for (int tt = 0; tt < 2; ++tt) {
      u32x4 v = (u32x4){0u, 0u, 0u, 0u};
      if (hi == 0) {
        int t = w * 64 + tt * 32 + col;
        v = (u32x4){pk2(s_g[0 * 256 + t], s_g[1 * 256 + t]),
                    pk2(s_g[2 * 256 + t], s_g[3 * 256 + t]),
                    pk2(s_g[4 * 256 + t], s_g[5 * 256 + t]),
                    pk2(s_g[6 * 256 + t], s_g[7 * 256 + t])};
      }
      gf[tt] = v;
    }
    #pragma unroll
    for (int ot = 0; ot < 4; ++ot) {
      u32x4 af = (u32x4){0u, 0u, 0u, 0u};
      if (hi == 0) {
        int o = ot * 32 + col;
        af = (u32x4){pk2(b2g[0 * 128 + o], b2g[1 * 128 + o]),
                     pk2(b2g[2 * 128 + o], b2g[3 * 128 + o]),
                     pk2(b2g[4 * 128 + o], b2g[5 * 128 + o]),
                     pk2(b2g[6 * 128 + o], b2g[7 * 128 + o])};
      }
      f32x16 z{};
      #pragma unroll
      for (int tt = 0; tt < 2; ++tt) acc2[ot][tt] = MFMA32(af, gf[tt], z);
    }
  }

  // ---- one chunk (tt=2): G1 16 MFMA -> EPI -> G2 16 MFMA (v8-proven)
  auto chunk = [&](const char* cb, int e, int ht, float g0, float g1) {
    f32x16 a1_0{}, a1_1{};
    __builtin_amdgcn_s_setprio(1);
    #pragma unroll
    for (int ks = 0; ks < 8; ++ks) {
      u32x4 f = *(const u32x4*)(cb + ks * 1024 + loff);
      a1_0 = MFMA32(f, xf[0][ks], a1_0);
      a1_1 = MFMA32(f, xf[1][ks], a1_1);
    }
    __builtin_amdgcn_s_setprio(0);

    const float* b1b = s_b1 + e * 256 + ht * 32 + hi * 4;
    u32x4 hf[2][2];
    #pragma unroll
    for (int tt = 0; tt < 2; ++tt) {
      const f32x16& a1 = tt ? a1_1 : a1_0;
      const float g = tt ? g1 : g0;
      u32 u[8];
      #pragma unroll
      for (int rg = 0; rg < 4; ++rg) {
        f32x4 bb = *(const f32x4*)(b1b + rg * 8);
        float h0 = fmaxf(a1[rg * 4 + 0] + bb.x, 0.f) * g;
        float h1 = fmaxf(a1[rg * 4 + 1] + bb.y, 0.f) * g;
        float h2 = fmaxf(a1[rg * 4 + 2] + bb.z, 0.f) * g;
        float h3 = fmaxf(a1[rg * 4 + 3] + bb.w, 0.f) * g;
        u[rg * 2 + 0] = pk2(h0, h1);
        u[rg * 2 + 1] = pk2(h2, h3);
      }
      pl32swap(u[0], u[2]);
      pl32swap(u[1], u[3]);
      pl32swap(u[4], u[6]);
      pl32swap(u[5], u[7]);
      hf[0][tt] = (u32x4){u[0], u[1], u[2], u[3]};
      hf[1][tt] = (u32x4){u[4], u[5], u[6], u[7]};
    }

    __builtin_amdgcn_s_setprio(1);
    #pragma unroll
    for (int ks2 = 0; ks2 < 2; ++ks2) {
      #pragma unroll
      for (int ot = 0; ot < 4; ++ot) {
        u32x4 af = *(const u32x4*)(cb + 8192 + (ks2 * 4 + ot) * 1024 + loff);
        acc2[ot][0] = MFMA32(af, hf[ks2][0], acc2[ot][0]);
        acc2[ot][1] = MFMA32(af, hf[ks2][1], acc2[ot][1]);
      }
    }
    __builtin_amdgcn_s_setprio(0);
  };

  // ---- main loop: iters chunk-pair iters; 1 barrier per 64 MFMA/wave
  #pragma unroll 1
  for (int i = 0; i < iters; ++i) {
    asm volatile("s_waitcnt vmcnt(0)" ::: "memory");  // stage from i-1 landed
    __builtin_amdgcn_s_barrier();
    __builtin_amdgcn_sched_barrier(0);
    if (i + 1 < iters) {
      const int j = i + 1;
      const int ej = (elist >> (4 * (j >> 2))) & 7;
      stage_pair(ej * 4 + (j & 3), j & 1);
    }
    const int ei = (elist >> (4 * (i >> 2))) & 7;
    const int ht0 = (i & 3) * 2;
    const float g0 = s_g[ei * 256 + w * 64 + col];
    const float g1 = s_g[ei * 256 + w * 64 + 32 + col];
    const char* buf = smem + (i & 1) * 32768;
    chunk(buf, ei, ht0, g0, g1);
    __builtin_amdgcn_sched_barrier(0);  // no cross-chunk frag hoisting
    chunk(buf + 16384, ei, ht0 + 1, g0, g1);
  }

  // ---- epilogue: reload perm (L2-hot) and scatter rows
  #pragma unroll
  for (int tt = 0; tt < 2; ++tt) {
    const u32 pt = perm[base + w * 64 + tt * 32 + col];
    #pragma unroll
    for (int ot = 0; ot < 4; ++ot) {
      const f32x16& a = acc2[ot][tt];
      float* op = out + (size_t)pt * 128 + ot * 32 + hi * 4;
      #pragma unroll
      for (int rg = 0; rg < 4; ++rg)
        *(f32x4*)(op + rg * 8) =
            (f32x4){a[rg * 4 + 0], a[rg * 4 + 1], a[rg * 4 + 2], a[rg * 4 + 3]};
    }
  }
}

extern "C" void kernel_launch(void* const* d_in, const int* in_sizes, int n_in,
                              void* d_out, int out_size, void* d_ws, size_t ws_size,
                              hipStream_t stream) {
  const float* x  = (const float*)d_in[0];
  const float* w1 = (const float*)d_in[1];
  const float* b1 = (const float*)d_in[2];
  const float* w2 = (const float*)d_in[3];
  const float* b2 = (const float*)d_in[4];
  const float* wg = (const float*)d_in[5];
  const float* bg = (const float*)d_in[6];
  float* out = (float*)d_out;

  int ntok = in_sizes[0] / 128;    // 131072
  int nblk = ntok / 256;           // 512

  // ws layout (bytes)
  char* ws = (char*)d_ws;
  char*  img    = ws;                        // 1,048,576
  u32*   hist   = (u32*)(ws + 1048576);      // 32,768 (128B-strided bins)
  u32*   cur2   = (u32*)(ws + 1081344);      // 32,768
  u32*   order  = (u32*)(ws + 1114112);      // 2,048
  u32*   umask  = (u32*)(ws + 1116160);      // 2,048
  u8*    maskA  = (u8*)(ws + 1118208);       // 131,072
  u32*   perm   = (u32*)(ws + 1249280);      // 524,288
  float* gw     = (float*)(ws + 1773568);    // 4,194,304
  if (ws_size < 5967872) return;

  hipMemsetAsync(hist, 0, 65536, stream);    // hist + cur2
  k1_img_gate<<<256 + nblk, 256, 0, stream>>>(w1, w2, img, x, wg, bg,
                                              gw, maskA, hist);
  k2_scatter<<<nblk + 1, 256, 0, stream>>>(hist, maskA, cur2, perm, order,
                                           umask);

  hipFuncSetAttribute(reinterpret_cast<const void*>(moe_main),
                      hipFuncAttributeMaxDynamicSharedMemorySize, SMEM_BYTES);
  moe_main<<<nblk, 256, SMEM_BYTES, stream>>>(x, b1, b2, img, perm, gw,
                                              order, umask, out);
}